// Round 11
// baseline (567.957 us; speedup 1.0000x reference)
//
#include <hip/hip_runtime.h>

#define N_NODES 20000
#define N_PAD   20480   // 160 row-blocks of 128 -> exact 8-XCD partition (20 each)
#define N_EDGES 320000
#define F_IN 512
#define F_OUT 1024
#define N_GRAPHS 64

typedef __attribute__((ext_vector_type(8))) short bf16x8;
typedef __attribute__((ext_vector_type(16))) float f32x16;
typedef __attribute__((ext_vector_type(8))) unsigned short ushort8v;

static __device__ __forceinline__ unsigned short f2bf(float f) {
    unsigned int u = __float_as_uint(f);
    u = (u + 0x7fff + ((u >> 16) & 1)) >> 16;   // RNE
    return (unsigned short)u;
}
static __device__ __forceinline__ float bf2f(unsigned short s) {
    return __uint_as_float(((unsigned int)s) << 16);
}

// ---------------- degree ----------------
__global__ void k_init(float* deg, int* cnt, int* cursor) {
    int i = blockIdx.x * 256 + threadIdx.x;
    if (i < N_NODES) { deg[i] = 1.0f; cnt[i] = 0; cursor[i] = 0; }
}

__global__ void k_deg(const int* __restrict__ dst, const float* __restrict__ ew,
                      float* deg, int* cnt) {
    int e = blockIdx.x * 256 + threadIdx.x;
    if (e < N_EDGES) {
        int d = dst[e];
        atomicAdd(&deg[d], ew[e]);
        atomicAdd(&cnt[d], 1);
    }
}

// ---------------- CSR build ----------------
__global__ __launch_bounds__(1024) void k_scan(const int* __restrict__ cnt, int* offs) {
    __shared__ int s[1024];
    int t = threadIdx.x;
    const int CH = (N_NODES + 1023) / 1024;
    int lo = t * CH, hi = min(lo + CH, N_NODES);
    int sum = 0;
    for (int i = lo; i < hi; i++) sum += cnt[i];
    s[t] = sum;
    __syncthreads();
    for (int off = 1; off < 1024; off <<= 1) {
        int v = (t >= off) ? s[t - off] : 0;
        __syncthreads();
        s[t] += v;
        __syncthreads();
    }
    int run = (t == 0) ? 0 : s[t - 1];
    for (int i = lo; i < hi; i++) { offs[i] = run; run += cnt[i]; }
    if (hi == N_NODES && lo < N_NODES) offs[N_NODES] = run;
}

// packed (src, weight-as-bits) per edge; dinv folded in via rsqrtf(deg)
__global__ void k_fill(const int* __restrict__ src, const int* __restrict__ dst,
                       const float* __restrict__ ew, const float* __restrict__ deg,
                       const int* __restrict__ offs, int* cursor,
                       int2* __restrict__ csre) {
    int e = blockIdx.x * 256 + threadIdx.x;
    if (e < N_EDGES) {
        int d = dst[e], s = src[e];
        int pos = offs[d] + atomicAdd(&cursor[d], 1);
        float w = rsqrtf(deg[s]) * ew[e] * rsqrtf(deg[d]);
        csre[pos] = make_int2(s, __float_as_int(w));
    }
}

// ---------------- conversions ----------------
__global__ void k_conv_x(const float* __restrict__ x, unsigned short* __restrict__ xb) {
    int idx = blockIdx.x * 256 + threadIdx.x;      // one thread = 8 cols
    int row = idx >> 6;                             // 64 chunks/row
    int c8 = (idx & 63) * 8;
    if (row >= N_PAD) return;
    ushort8v v;
    if (row < N_NODES) {
        const float* p = &x[(size_t)row * F_IN + c8];
#pragma unroll
        for (int i = 0; i < 8; i++) v[i] = f2bf(p[i]);
    } else {
#pragma unroll
        for (int i = 0; i < 8; i++) v[i] = 0;
    }
    *(ushort8v*)&xb[(size_t)row * F_IN + c8] = v;
}

// W [K][1024] f32 -> Wt [1024][K] bf16 (tiled transpose)
__global__ __launch_bounds__(256) void k_conv_wt(const float* __restrict__ W,
                                                 unsigned short* __restrict__ Wt, int K) {
    __shared__ float tile[32][33];
    int n0 = blockIdx.x * 32;
    int k0 = blockIdx.y * 32;
    int tx = threadIdx.x & 31;
    int ty = threadIdx.x >> 5;   // 0..7
#pragma unroll
    for (int i = 0; i < 32; i += 8)
        tile[ty + i][tx] = W[(size_t)(k0 + ty + i) * F_OUT + n0 + tx];
    __syncthreads();
#pragma unroll
    for (int i = 0; i < 32; i += 8)
        Wt[(size_t)(n0 + ty + i) * K + k0 + tx] = f2bf(tile[tx][ty + i]);
}

// ---------------- slab aggregation (layer 1, X-space): 1 wave = 8 nodes x 64-col slab ----------------
__global__ __launch_bounds__(64) void k_aggr_slab(const unsigned short* __restrict__ xin,
                                                  const float* __restrict__ deg,
                                                  const int* __restrict__ offs,
                                                  const int2* __restrict__ csre,
                                                  unsigned short* __restrict__ outp,
                                                  int F) {
    const int bid = blockIdx.x;
    const int slab = bid & 7;
    const int ng = bid >> 3;
    const int lane = threadIdx.x;
    const int n = ng * 8 + (lane >> 3);
    const int c = slab * 64 + (lane & 7) * 8;

    if (n >= N_NODES) {
        ushort8v z;
#pragma unroll
        for (int i = 0; i < 8; i++) z[i] = 0;
        *(ushort8v*)&outp[(size_t)n * F + c] = z;
        return;
    }

    const float di = rsqrtf(deg[n]);
    const float wself = di * di;
    float a[8];
    {
        ushort8v v = *(const ushort8v*)&xin[(size_t)n * F + c];
#pragma unroll
        for (int i = 0; i < 8; i++) a[i] = bf2f(v[i]) * wself;
    }

    const int lo = offs[n], hi = offs[n + 1];
    int j = lo;
    for (; j + 8 <= hi; j += 8) {
        int2 e[8];
#pragma unroll
        for (int q = 0; q < 8; q++) e[q] = csre[j + q];
        ushort8v u[8];
#pragma unroll
        for (int q = 0; q < 8; q++) u[q] = *(const ushort8v*)&xin[(size_t)e[q].x * F + c];
#pragma unroll
        for (int q = 0; q < 8; q++) {
            float w = __int_as_float(e[q].y);
#pragma unroll
            for (int i = 0; i < 8; i++) a[i] += w * bf2f(u[q][i]);
        }
    }
    for (; j < hi; j++) {
        int2 e = csre[j];
        float w = __int_as_float(e.y);
        ushort8v u = *(const ushort8v*)&xin[(size_t)e.x * F + c];
#pragma unroll
        for (int i = 0; i < 8; i++) a[i] += w * bf2f(u[i]);
    }

    ushort8v r;
#pragma unroll
    for (int i = 0; i < 8; i++) r[i] = f2bf(a[i]);
    *(ushort8v*)&outp[(size_t)n * F + c] = r;
}

// ---------------- fused layer-2 aggregation + bias + relu + mean-pool ----------------
// Same gather structure, but instead of writing h2, scale by 1/cnt[g], butterfly-
// reduce the 8 nodes of the wave (all-same-graph fast path; N_NODES = 2500*8 so
// every wave holds 8 full real rows), and atomicAdd into out[64][1024].
__global__ __launch_bounds__(64) void k_aggr_pool(const unsigned short* __restrict__ xin,
                                                  const float* __restrict__ deg,
                                                  const int* __restrict__ offs,
                                                  const int2* __restrict__ csre,
                                                  const float* __restrict__ bias,
                                                  const int* __restrict__ batch,
                                                  const int* __restrict__ gstart,
                                                  float* __restrict__ out) {
    const int bid = blockIdx.x;
    const int slab = bid & 7;
    const int ng = bid >> 3;                       // 0..2499, all real
    const int lane = threadIdx.x;
    const int nsub = lane >> 3;
    const int n = ng * 8 + nsub;
    const int c = blockIdx.y * 512 + slab * 64 + (lane & 7) * 8;

    const float di = rsqrtf(deg[n]);
    const float wself = di * di;
    float a[8];
    {
        ushort8v v = *(const ushort8v*)&xin[(size_t)n * F_OUT + c];
#pragma unroll
        for (int i = 0; i < 8; i++) a[i] = bf2f(v[i]) * wself;
    }

    const int lo = offs[n], hi = offs[n + 1];
    int j = lo;
    for (; j + 8 <= hi; j += 8) {
        int2 e[8];
#pragma unroll
        for (int q = 0; q < 8; q++) e[q] = csre[j + q];
        ushort8v u[8];
#pragma unroll
        for (int q = 0; q < 8; q++) u[q] = *(const ushort8v*)&xin[(size_t)e[q].x * F_OUT + c];
#pragma unroll
        for (int q = 0; q < 8; q++) {
            float w = __int_as_float(e[q].y);
#pragma unroll
            for (int i = 0; i < 8; i++) a[i] += w * bf2f(u[q][i]);
        }
    }
    for (; j < hi; j++) {
        int2 e = csre[j];
        float w = __int_as_float(e.y);
        ushort8v u = *(const ushort8v*)&xin[(size_t)e.x * F_OUT + c];
#pragma unroll
        for (int i = 0; i < 8; i++) a[i] += w * bf2f(u[i]);
    }

    // epilogue: bias + relu + scale by 1/count(graph)
    const int g = batch[n];
    const float inv = 1.0f / (float)max(gstart[g + 1] - gstart[g], 1);
#pragma unroll
    for (int i = 0; i < 8; i++)
        a[i] = fmaxf(a[i] + bias[c + i], 0.f) * inv;

    // wave-uniform check: 8 consecutive nodes in one graph? (batch sorted)
    const bool uni = (batch[ng * 8] == batch[ng * 8 + 7]);
    if (uni) {
#pragma unroll
        for (int m = 8; m < 64; m <<= 1)
#pragma unroll
            for (int i = 0; i < 8; i++) a[i] += __shfl_xor(a[i], m, 64);
        if (nsub == 0) {
#pragma unroll
            for (int i = 0; i < 8; i++)
                atomicAdd(&out[(size_t)g * F_OUT + c + i], a[i]);
        }
    } else {   // rare boundary wave: per-node atomics
#pragma unroll
        for (int i = 0; i < 8; i++)
            atomicAdd(&out[(size_t)g * F_OUT + c + i], a[i]);
    }
}

// ---------------- bf16 MFMA GEMM (32x32x16): C_bf16[N_PAD,1024] = A @ Bt^T ----------------
// xcd=bid&7 owns row-blocks [xcd*20, xcd*20+20), col-block fastest -> 5.1 MB A-slice
// L2-resident per XCD. XOR-swizzled LDS staging (chunk ^= (r>>1)&3), 0 bank conflicts.
// C/D: col=lane&31, row=(reg&3)+8*(reg>>2)+4*(lane>>5)  [m74/m101].
__global__ __launch_bounds__(256) void k_gemm_bf16(const unsigned short* __restrict__ A,
                                                   const unsigned short* __restrict__ Bt,
                                                   unsigned short* __restrict__ C, int K,
                                                   const float* __restrict__ bias, int act) {
    __shared__ short As[128 * 32];
    __shared__ short Bs[128 * 32];
    const int bid = blockIdx.x;
    const int xcd = bid & 7;
    const int i2 = bid >> 3;                 // 0..159
    const int colb = i2 & 7;
    const int rowb = xcd * 20 + (i2 >> 3);   // exact partition: 8 XCD x 20 row-blocks
    const int row0 = rowb * 128;
    const int col0 = colb * 128;

    const int tid = threadIdx.x;
    const int lane = tid & 63;
    const int wave = tid >> 6;
    const int wm = wave >> 1, wn = wave & 1;
    const int l5 = lane & 31;
    const int kh = lane >> 5;                // k-half within a 16-k step

    f32x16 acc[2][2] = {};

    for (int k0 = 0; k0 < K; k0 += 32) {
#pragma unroll
        for (int it = 0; it < 2; it++) {
            int idx = it * 256 + tid;              // LDS chunk id 0..511 (lane-linear dest)
            int r = idx >> 2;
            int kc = (idx & 3) ^ ((r >> 1) & 3);   // swizzled global k-chunk
            const unsigned short* ga = &A[(size_t)(row0 + r) * K + k0 + kc * 8];
            __builtin_amdgcn_global_load_lds(
                (const __attribute__((address_space(1))) void*)ga,
                (__attribute__((address_space(3))) void*)&As[idx * 8], 16, 0, 0);
            const unsigned short* gb = &Bt[(size_t)(col0 + r) * K + k0 + kc * 8];
            __builtin_amdgcn_global_load_lds(
                (const __attribute__((address_space(1))) void*)gb,
                (__attribute__((address_space(3))) void*)&Bs[idx * 8], 16, 0, 0);
        }
        __syncthreads();

        bf16x8 af[2][2], bfr[2][2];   // [kk][tile]
#pragma unroll
        for (int kk = 0; kk < 2; kk++) {
            int g = kk * 2 + kh;      // global 8-elem k-chunk for this lane
#pragma unroll
            for (int i = 0; i < 2; i++) {
                int ar = wm * 64 + i * 32 + l5;
                int ac = g ^ ((ar >> 1) & 3);
                af[kk][i] = *(const bf16x8*)&As[ar * 32 + ac * 8];
            }
#pragma unroll
            for (int j = 0; j < 2; j++) {
                int br = wn * 64 + j * 32 + l5;
                int bc = g ^ ((br >> 1) & 3);
                bfr[kk][j] = *(const bf16x8*)&Bs[br * 32 + bc * 8];
            }
        }
#pragma unroll
        for (int kk = 0; kk < 2; kk++)
#pragma unroll
            for (int i = 0; i < 2; i++)
#pragma unroll
                for (int j = 0; j < 2; j++)
                    acc[i][j] = __builtin_amdgcn_mfma_f32_32x32x16_bf16(
                        af[kk][i], bfr[kk][j], acc[i][j], 0, 0, 0);
        __syncthreads();
    }

#pragma unroll
    for (int i = 0; i < 2; i++) {
#pragma unroll
        for (int j = 0; j < 2; j++) {
            int rbase = row0 + wm * 64 + i * 32 + kh * 4;
            int c = col0 + wn * 64 + j * 32 + l5;
            float bv = act ? bias[c] : 0.f;
#pragma unroll
            for (int reg = 0; reg < 16; reg++) {
                int rrow = rbase + (reg & 3) + 8 * (reg >> 2);
                float v = acc[i][j][reg];
                if (act) v = fmaxf(v + bv, 0.f);
                C[(size_t)rrow * F_OUT + c] = f2bf(v);
            }
        }
    }
}

// ---------------- pooling helpers ----------------
__global__ void k_gstart(const int* __restrict__ batch, int* gstart) {
    int g = threadIdx.x;
    if (g > N_GRAPHS) return;
    if (g == N_GRAPHS) { gstart[g] = N_NODES; return; }
    int lo = 0, hi = N_NODES;
    while (lo < hi) {
        int mid = (lo + hi) >> 1;
        if (batch[mid] < g) lo = mid + 1; else hi = mid;
    }
    gstart[g] = lo;
}

__global__ void k_zero_out(float* out) {
    int i = blockIdx.x * 256 + threadIdx.x;
    if (i < N_GRAPHS * F_OUT) out[i] = 0.f;
}

// ---------------- launch ----------------
extern "C" void kernel_launch(void* const* d_in, const int* in_sizes, int n_in,
                              void* d_out, int out_size, void* d_ws, size_t ws_size,
                              hipStream_t stream) {
    const float* x    = (const float*)d_in[0];
    const int* ei     = (const int*)d_in[1];
    const float* ew   = (const float*)d_in[2];
    const int* batch  = (const int*)d_in[3];
    const float* W1   = (const float*)d_in[4];
    const float* b1   = (const float*)d_in[5];
    const float* W2   = (const float*)d_in[6];
    const float* b2   = (const float*)d_in[7];
    float* out = (float*)d_out;

    const int* src = ei;
    const int* dst = ei + N_EDGES;

    char* ws = (char*)d_ws;
    const size_t SZ_XB  = (size_t)N_PAD * F_IN * 2;    // 21.0 MB
    const size_t SZ_AX  = (size_t)N_PAD * F_IN * 2;    // 21.0 MB
    const size_t SZ_WT1 = (size_t)F_OUT * F_IN * 2;    //  1 MB
    const size_t SZ_WT2 = (size_t)F_OUT * F_OUT * 2;   //  2 MB
    const size_t SZ_B   = (size_t)N_PAD * F_OUT * 2;   // 41.9 MB
    unsigned short* xb  = (unsigned short*)(ws);
    unsigned short* ax  = (unsigned short*)(ws + SZ_XB);
    unsigned short* Wt1 = (unsigned short*)(ws + SZ_XB + SZ_AX);
    unsigned short* Wt2 = (unsigned short*)(ws + SZ_XB + SZ_AX + SZ_WT1);
    unsigned short* h1  = (unsigned short*)(ws + SZ_XB + SZ_AX + SZ_WT1 + SZ_WT2);
    unsigned short* xw2 = (unsigned short*)(ws + SZ_XB + SZ_AX + SZ_WT1 + SZ_WT2 + SZ_B);
    size_t off = SZ_XB + SZ_AX + SZ_WT1 + SZ_WT2 + 2 * SZ_B;
    auto alloc = [&](size_t bytes) -> void* {
        void* p = ws + off;
        off += (bytes + 255) & ~(size_t)255;
        return p;
    };
    float* deg    = (float*)alloc((size_t)N_NODES * 4);
    int*   cnt    = (int*)  alloc((size_t)N_NODES * 4);
    int*   offs   = (int*)  alloc((size_t)(N_NODES + 1) * 4);
    int*   cursor = (int*)  alloc((size_t)N_NODES * 4);
    int2*  csre   = (int2*) alloc((size_t)N_EDGES * 8);
    int*   gstart = (int*)  alloc((size_t)(N_GRAPHS + 1) * 4);

    const int nb_n = (N_NODES + 255) / 256;
    const int nb_e = (N_EDGES + 255) / 256;

    k_init<<<nb_n, 256, 0, stream>>>(deg, cnt, cursor);
    k_deg<<<nb_e, 256, 0, stream>>>(dst, ew, deg, cnt);
    k_scan<<<1, 1024, 0, stream>>>(cnt, offs);
    k_fill<<<nb_e, 256, 0, stream>>>(src, dst, ew, deg, offs, cursor, csre);
    k_gstart<<<1, 128, 0, stream>>>(batch, gstart);
    k_zero_out<<<(N_GRAPHS * F_OUT + 255) / 256, 256, 0, stream>>>(out);

    // conversions
    k_conv_x<<<(N_PAD * (F_IN / 8) + 255) / 256, 256, 0, stream>>>(x, xb);
    k_conv_wt<<<dim3(F_OUT / 32, F_IN / 32), 256, 0, stream>>>(W1, Wt1, F_IN);
    k_conv_wt<<<dim3(F_OUT / 32, F_OUT / 32), 256, 0, stream>>>(W2, Wt2, F_OUT);

    // layer 1: aggregate X first (reassociated), then GEMM with fused bias+relu
    k_aggr_slab<<<(N_PAD / 8) * 8, 64, 0, stream>>>(xb, deg, offs, csre, ax, F_IN);
    const int gemm_blocks = (N_PAD / 128) * (F_OUT / 128);   // 1280
    k_gemm_bf16<<<gemm_blocks, 256, 0, stream>>>(ax, Wt1, h1, F_IN, b1, 1);
    // layer 2: GEMM -> fused aggregation + bias + relu + mean-pool
    k_gemm_bf16<<<gemm_blocks, 256, 0, stream>>>(h1, Wt2, xw2, F_OUT, (const float*)nullptr, 0);
    k_aggr_pool<<<dim3((N_NODES / 8) * 8, 2), 64, 0, stream>>>(xw2, deg, offs, csre,
                                                               b2, batch, gstart, out);
}

// Round 12
// 392.128 us; speedup vs baseline: 1.4484x; 1.4484x over previous
//
#include <hip/hip_runtime.h>

#define N_NODES 20000
#define N_PAD   20480   // 160 row-blocks of 128 -> exact 8-XCD partition (20 each)
#define N_EDGES 320000
#define F_IN 512
#define F_OUT 1024
#define N_GRAPHS 64

typedef __attribute__((ext_vector_type(8))) short bf16x8;
typedef __attribute__((ext_vector_type(16))) float f32x16;
typedef __attribute__((ext_vector_type(8))) unsigned short ushort8v;

static __device__ __forceinline__ unsigned short f2bf(float f) {
    unsigned int u = __float_as_uint(f);
    u = (u + 0x7fff + ((u >> 16) & 1)) >> 16;   // RNE
    return (unsigned short)u;
}
static __device__ __forceinline__ float bf2f(unsigned short s) {
    return __uint_as_float(((unsigned int)s) << 16);
}

// ---------------- degree ----------------
__global__ void k_init(float* deg, int* cnt, int* cursor) {
    int i = blockIdx.x * 256 + threadIdx.x;
    if (i < N_NODES) { deg[i] = 1.0f; cnt[i] = 0; cursor[i] = 0; }
}

__global__ void k_deg(const int* __restrict__ dst, const float* __restrict__ ew,
                      float* deg, int* cnt) {
    int e = blockIdx.x * 256 + threadIdx.x;
    if (e < N_EDGES) {
        int d = dst[e];
        atomicAdd(&deg[d], ew[e]);
        atomicAdd(&cnt[d], 1);
    }
}

// ---------------- CSR build ----------------
__global__ __launch_bounds__(1024) void k_scan(const int* __restrict__ cnt, int* offs) {
    __shared__ int s[1024];
    int t = threadIdx.x;
    const int CH = (N_NODES + 1023) / 1024;
    int lo = t * CH, hi = min(lo + CH, N_NODES);
    int sum = 0;
    for (int i = lo; i < hi; i++) sum += cnt[i];
    s[t] = sum;
    __syncthreads();
    for (int off = 1; off < 1024; off <<= 1) {
        int v = (t >= off) ? s[t - off] : 0;
        __syncthreads();
        s[t] += v;
        __syncthreads();
    }
    int run = (t == 0) ? 0 : s[t - 1];
    for (int i = lo; i < hi; i++) { offs[i] = run; run += cnt[i]; }
    if (hi == N_NODES && lo < N_NODES) offs[N_NODES] = run;
}

// packed (src, weight-as-bits) per edge; dinv folded in via rsqrtf(deg)
__global__ void k_fill(const int* __restrict__ src, const int* __restrict__ dst,
                       const float* __restrict__ ew, const float* __restrict__ deg,
                       const int* __restrict__ offs, int* cursor,
                       int2* __restrict__ csre) {
    int e = blockIdx.x * 256 + threadIdx.x;
    if (e < N_EDGES) {
        int d = dst[e], s = src[e];
        int pos = offs[d] + atomicAdd(&cursor[d], 1);
        float w = rsqrtf(deg[s]) * ew[e] * rsqrtf(deg[d]);
        csre[pos] = make_int2(s, __float_as_int(w));
    }
}

// ---------------- conversions ----------------
__global__ void k_conv_x(const float* __restrict__ x, unsigned short* __restrict__ xb) {
    int idx = blockIdx.x * 256 + threadIdx.x;      // one thread = 8 cols
    int row = idx >> 6;                             // 64 chunks/row
    int c8 = (idx & 63) * 8;
    if (row >= N_PAD) return;
    ushort8v v;
    if (row < N_NODES) {
        const float* p = &x[(size_t)row * F_IN + c8];
#pragma unroll
        for (int i = 0; i < 8; i++) v[i] = f2bf(p[i]);
    } else {
#pragma unroll
        for (int i = 0; i < 8; i++) v[i] = 0;
    }
    *(ushort8v*)&xb[(size_t)row * F_IN + c8] = v;
}

// W [K][1024] f32 -> Wt [1024][K] bf16 (tiled transpose)
__global__ __launch_bounds__(256) void k_conv_wt(const float* __restrict__ W,
                                                 unsigned short* __restrict__ Wt, int K) {
    __shared__ float tile[32][33];
    int n0 = blockIdx.x * 32;
    int k0 = blockIdx.y * 32;
    int tx = threadIdx.x & 31;
    int ty = threadIdx.x >> 5;   // 0..7
#pragma unroll
    for (int i = 0; i < 32; i += 8)
        tile[ty + i][tx] = W[(size_t)(k0 + ty + i) * F_OUT + n0 + tx];
    __syncthreads();
#pragma unroll
    for (int i = 0; i < 32; i += 8)
        Wt[(size_t)(n0 + ty + i) * K + k0 + tx] = f2bf(tile[tx][ty + i]);
}

// ---------------- slab aggregation: 1 wave = 8 nodes x one 64-col slab ----------------
// 4x-unrolled edge loop (R9 config: VGPR ~16, occupancy ~76% -- 8x regressed TLP).
__global__ __launch_bounds__(64) void k_aggr_slab(const unsigned short* __restrict__ xin,
                                                  const float* __restrict__ deg,
                                                  const int* __restrict__ offs,
                                                  const int2* __restrict__ csre,
                                                  const float* __restrict__ bias,
                                                  unsigned short* __restrict__ outp,
                                                  int F, int act) {
    const int bid = blockIdx.x;
    const int slab = bid & 7;
    const int ng = bid >> 3;
    const int lane = threadIdx.x;
    const int n = ng * 8 + (lane >> 3);
    const int c = blockIdx.y * 512 + slab * 64 + (lane & 7) * 8;

    if (n >= N_NODES) {
        ushort8v z;
#pragma unroll
        for (int i = 0; i < 8; i++) z[i] = 0;
        *(ushort8v*)&outp[(size_t)n * F + c] = z;
        return;
    }

    const float di = rsqrtf(deg[n]);
    const float wself = di * di;
    float a[8];
    {
        ushort8v v = *(const ushort8v*)&xin[(size_t)n * F + c];
#pragma unroll
        for (int i = 0; i < 8; i++) a[i] = bf2f(v[i]) * wself;
    }

    const int lo = offs[n], hi = offs[n + 1];
    int j = lo;
    for (; j + 4 <= hi; j += 4) {
        int2 e0 = csre[j + 0];
        int2 e1 = csre[j + 1];
        int2 e2 = csre[j + 2];
        int2 e3 = csre[j + 3];
        ushort8v u0 = *(const ushort8v*)&xin[(size_t)e0.x * F + c];
        ushort8v u1 = *(const ushort8v*)&xin[(size_t)e1.x * F + c];
        ushort8v u2 = *(const ushort8v*)&xin[(size_t)e2.x * F + c];
        ushort8v u3 = *(const ushort8v*)&xin[(size_t)e3.x * F + c];
        float w0 = __int_as_float(e0.y);
        float w1 = __int_as_float(e1.y);
        float w2 = __int_as_float(e2.y);
        float w3 = __int_as_float(e3.y);
#pragma unroll
        for (int i = 0; i < 8; i++) {
            a[i] += w0 * bf2f(u0[i]);
            a[i] += w1 * bf2f(u1[i]);
            a[i] += w2 * bf2f(u2[i]);
            a[i] += w3 * bf2f(u3[i]);
        }
    }
    for (; j < hi; j++) {
        int2 e = csre[j];
        float w = __int_as_float(e.y);
        ushort8v u = *(const ushort8v*)&xin[(size_t)e.x * F + c];
#pragma unroll
        for (int i = 0; i < 8; i++) a[i] += w * bf2f(u[i]);
    }

    ushort8v r;
    if (act) {
#pragma unroll
        for (int i = 0; i < 8; i++) r[i] = f2bf(fmaxf(a[i] + bias[c + i], 0.f));
    } else {
#pragma unroll
        for (int i = 0; i < 8; i++) r[i] = f2bf(a[i]);
    }
    *(ushort8v*)&outp[(size_t)n * F + c] = r;
}

// ---------------- bf16 MFMA GEMM (32x32x16): C_bf16[N_PAD,1024] = A @ Bt^T ----------------
// xcd=bid&7 owns row-blocks [xcd*20, xcd*20+20), col-block fastest -> 5.1 MB A-slice
// L2-resident per XCD. XOR-swizzled LDS staging (chunk ^= (r>>1)&3), 0 bank conflicts.
// C/D: col=lane&31, row=(reg&3)+8*(reg>>2)+4*(lane>>5)  [m74/m101].
__global__ __launch_bounds__(256) void k_gemm_bf16(const unsigned short* __restrict__ A,
                                                   const unsigned short* __restrict__ Bt,
                                                   unsigned short* __restrict__ C, int K,
                                                   const float* __restrict__ bias, int act) {
    __shared__ short As[128 * 32];
    __shared__ short Bs[128 * 32];
    const int bid = blockIdx.x;
    const int xcd = bid & 7;
    const int i2 = bid >> 3;                 // 0..159
    const int colb = i2 & 7;
    const int rowb = xcd * 20 + (i2 >> 3);   // exact partition: 8 XCD x 20 row-blocks
    const int row0 = rowb * 128;
    const int col0 = colb * 128;

    const int tid = threadIdx.x;
    const int lane = tid & 63;
    const int wave = tid >> 6;
    const int wm = wave >> 1, wn = wave & 1;
    const int l5 = lane & 31;
    const int kh = lane >> 5;                // k-half within a 16-k step

    f32x16 acc[2][2] = {};

    for (int k0 = 0; k0 < K; k0 += 32) {
#pragma unroll
        for (int it = 0; it < 2; it++) {
            int idx = it * 256 + tid;              // LDS chunk id 0..511 (lane-linear dest)
            int r = idx >> 2;
            int kc = (idx & 3) ^ ((r >> 1) & 3);   // swizzled global k-chunk
            const unsigned short* ga = &A[(size_t)(row0 + r) * K + k0 + kc * 8];
            __builtin_amdgcn_global_load_lds(
                (const __attribute__((address_space(1))) void*)ga,
                (__attribute__((address_space(3))) void*)&As[idx * 8], 16, 0, 0);
            const unsigned short* gb = &Bt[(size_t)(col0 + r) * K + k0 + kc * 8];
            __builtin_amdgcn_global_load_lds(
                (const __attribute__((address_space(1))) void*)gb,
                (__attribute__((address_space(3))) void*)&Bs[idx * 8], 16, 0, 0);
        }
        __syncthreads();

        bf16x8 af[2][2], bfr[2][2];   // [kk][tile]
#pragma unroll
        for (int kk = 0; kk < 2; kk++) {
            int g = kk * 2 + kh;      // global 8-elem k-chunk for this lane
#pragma unroll
            for (int i = 0; i < 2; i++) {
                int ar = wm * 64 + i * 32 + l5;
                int ac = g ^ ((ar >> 1) & 3);
                af[kk][i] = *(const bf16x8*)&As[ar * 32 + ac * 8];
            }
#pragma unroll
            for (int j = 0; j < 2; j++) {
                int br = wn * 64 + j * 32 + l5;
                int bc = g ^ ((br >> 1) & 3);
                bfr[kk][j] = *(const bf16x8*)&Bs[br * 32 + bc * 8];
            }
        }
#pragma unroll
        for (int kk = 0; kk < 2; kk++)
#pragma unroll
            for (int i = 0; i < 2; i++)
#pragma unroll
                for (int j = 0; j < 2; j++)
                    acc[i][j] = __builtin_amdgcn_mfma_f32_32x32x16_bf16(
                        af[kk][i], bfr[kk][j], acc[i][j], 0, 0, 0);
        __syncthreads();
    }

#pragma unroll
    for (int i = 0; i < 2; i++) {
#pragma unroll
        for (int j = 0; j < 2; j++) {
            int rbase = row0 + wm * 64 + i * 32 + kh * 4;
            int c = col0 + wn * 64 + j * 32 + l5;
            float bv = act ? bias[c] : 0.f;
#pragma unroll
            for (int reg = 0; reg < 16; reg++) {
                int rrow = rbase + (reg & 3) + 8 * (reg >> 2);
                float v = acc[i][j][reg];
                if (act) v = fmaxf(v + bv, 0.f);
                C[(size_t)rrow * F_OUT + c] = f2bf(v);
            }
        }
    }
}

// ---------------- pooling ----------------
__global__ void k_gstart(const int* __restrict__ batch, int* gstart) {
    int g = threadIdx.x;
    if (g > N_GRAPHS) return;
    if (g == N_GRAPHS) { gstart[g] = N_NODES; return; }
    int lo = 0, hi = N_NODES;
    while (lo < hi) {
        int mid = (lo + hi) >> 1;
        if (batch[mid] < g) lo = mid + 1; else hi = mid;
    }
    gstart[g] = lo;
}

__global__ void k_zero_out(float* out) {
    int i = blockIdx.x * 256 + threadIdx.x;
    if (i < N_GRAPHS * F_OUT) out[i] = 0.f;
}

// node-parallel mean-pool
__global__ __launch_bounds__(256) void k_pool(const unsigned short* __restrict__ h,
                                              const int* __restrict__ batch,
                                              const int* __restrict__ gstart,
                                              float* __restrict__ out) {
    const int r0 = blockIdx.x * 64;
    const int rowsub = threadIdx.x >> 7;           // 0..1
    const int c = (threadIdx.x & 127) * 8;         // full 1024-col row
    const int rend = min(r0 + 64, N_NODES);
    int row = r0 + rowsub;
    if (row >= rend) return;

    float a[8] = {};
    int gcur = batch[row];
    for (; row < rend; row += 2) {
        int g = batch[row];
        if (g != gcur) {
            float inv = 1.0f / (float)max(gstart[gcur + 1] - gstart[gcur], 1);
#pragma unroll
            for (int i = 0; i < 8; i++) {
                atomicAdd(&out[(size_t)gcur * F_OUT + c + i], a[i] * inv);
                a[i] = 0.f;
            }
            gcur = g;
        }
        ushort8v v = *(const ushort8v*)&h[(size_t)row * F_OUT + c];
#pragma unroll
        for (int i = 0; i < 8; i++) a[i] += bf2f(v[i]);
    }
    float inv = 1.0f / (float)max(gstart[gcur + 1] - gstart[gcur], 1);
#pragma unroll
    for (int i = 0; i < 8; i++)
        atomicAdd(&out[(size_t)gcur * F_OUT + c + i], a[i] * inv);
}

// ---------------- launch ----------------
extern "C" void kernel_launch(void* const* d_in, const int* in_sizes, int n_in,
                              void* d_out, int out_size, void* d_ws, size_t ws_size,
                              hipStream_t stream) {
    const float* x    = (const float*)d_in[0];
    const int* ei     = (const int*)d_in[1];
    const float* ew   = (const float*)d_in[2];
    const int* batch  = (const int*)d_in[3];
    const float* W1   = (const float*)d_in[4];
    const float* b1   = (const float*)d_in[5];
    const float* W2   = (const float*)d_in[6];
    const float* b2   = (const float*)d_in[7];
    float* out = (float*)d_out;

    const int* src = ei;
    const int* dst = ei + N_EDGES;

    char* ws = (char*)d_ws;
    const size_t SZ_XB  = (size_t)N_PAD * F_IN * 2;    // 21.0 MB
    const size_t SZ_AX  = (size_t)N_PAD * F_IN * 2;    // 21.0 MB
    const size_t SZ_WT1 = (size_t)F_OUT * F_IN * 2;    //  1 MB
    const size_t SZ_WT2 = (size_t)F_OUT * F_OUT * 2;   //  2 MB
    const size_t SZ_B   = (size_t)N_PAD * F_OUT * 2;   // 41.9 MB
    unsigned short* xb  = (unsigned short*)(ws);
    unsigned short* ax  = (unsigned short*)(ws + SZ_XB);
    unsigned short* Wt1 = (unsigned short*)(ws + SZ_XB + SZ_AX);
    unsigned short* Wt2 = (unsigned short*)(ws + SZ_XB + SZ_AX + SZ_WT1);
    unsigned short* h1  = (unsigned short*)(ws + SZ_XB + SZ_AX + SZ_WT1 + SZ_WT2);
    unsigned short* xw2 = (unsigned short*)(ws + SZ_XB + SZ_AX + SZ_WT1 + SZ_WT2 + SZ_B);
    unsigned short* h2  = (unsigned short*)(ws);       // aliases xb/ax (dead in phase B)
    size_t off = SZ_XB + SZ_AX + SZ_WT1 + SZ_WT2 + 2 * SZ_B;
    auto alloc = [&](size_t bytes) -> void* {
        void* p = ws + off;
        off += (bytes + 255) & ~(size_t)255;
        return p;
    };
    float* deg    = (float*)alloc((size_t)N_NODES * 4);
    int*   cnt    = (int*)  alloc((size_t)N_NODES * 4);
    int*   offs   = (int*)  alloc((size_t)(N_NODES + 1) * 4);
    int*   cursor = (int*)  alloc((size_t)N_NODES * 4);
    int2*  csre   = (int2*) alloc((size_t)N_EDGES * 8);
    int*   gstart = (int*)  alloc((size_t)(N_GRAPHS + 1) * 4);

    const int nb_n = (N_NODES + 255) / 256;
    const int nb_e = (N_EDGES + 255) / 256;

    k_init<<<nb_n, 256, 0, stream>>>(deg, cnt, cursor);
    k_deg<<<nb_e, 256, 0, stream>>>(dst, ew, deg, cnt);
    k_scan<<<1, 1024, 0, stream>>>(cnt, offs);
    k_fill<<<nb_e, 256, 0, stream>>>(src, dst, ew, deg, offs, cursor, csre);
    k_gstart<<<1, 128, 0, stream>>>(batch, gstart);
    k_zero_out<<<(N_GRAPHS * F_OUT + 255) / 256, 256, 0, stream>>>(out);

    // conversions
    k_conv_x<<<(N_PAD * (F_IN / 8) + 255) / 256, 256, 0, stream>>>(x, xb);
    k_conv_wt<<<dim3(F_OUT / 32, F_IN / 32), 256, 0, stream>>>(W1, Wt1, F_IN);
    k_conv_wt<<<dim3(F_OUT / 32, F_OUT / 32), 256, 0, stream>>>(W2, Wt2, F_OUT);

    // layer 1: aggregate X first (reassociated), then GEMM with fused bias+relu
    k_aggr_slab<<<dim3((N_PAD / 8) * 8, 1), 64, 0, stream>>>(xb, deg, offs, csre,
                                                             (const float*)nullptr, ax, F_IN, 0);
    const int gemm_blocks = (N_PAD / 128) * (F_OUT / 128);   // 1280
    k_gemm_bf16<<<gemm_blocks, 256, 0, stream>>>(ax, Wt1, h1, F_IN, b1, 1);
    // layer 2: GEMM then slab aggregation with fused bias+relu -> h2
    k_gemm_bf16<<<gemm_blocks, 256, 0, stream>>>(h1, Wt2, xw2, F_OUT, (const float*)nullptr, 0);
    k_aggr_slab<<<dim3((N_PAD / 8) * 8, 2), 64, 0, stream>>>(xw2, deg, offs, csre, b2, h2, F_OUT, 1);
    // pool (node-parallel)
    k_pool<<<(N_NODES + 63) / 64, 256, 0, stream>>>(h2, batch, gstart, out);
}

// Round 13
// 388.290 us; speedup vs baseline: 1.4627x; 1.0099x over previous
//
#include <hip/hip_runtime.h>

#define N_NODES 20000
#define N_PAD   20480   // 160 row-blocks of 128 -> exact 8-XCD partition (20 each)
#define N_EDGES 320000
#define F_IN 512
#define F_OUT 1024
#define N_GRAPHS 64

typedef __attribute__((ext_vector_type(8))) short bf16x8;
typedef __attribute__((ext_vector_type(16))) float f32x16;
typedef __attribute__((ext_vector_type(8))) unsigned short ushort8v;

static __device__ __forceinline__ unsigned short f2bf(float f) {
    unsigned int u = __float_as_uint(f);
    u = (u + 0x7fff + ((u >> 16) & 1)) >> 16;   // RNE
    return (unsigned short)u;
}
static __device__ __forceinline__ float bf2f(unsigned short s) {
    return __uint_as_float(((unsigned int)s) << 16);
}

// ---------------- fused setup: deg/cnt/cursor init + out zero + gstart ----------------
__global__ void k_setup(float* deg, int* cnt, int* cursor, float* out,
                        const int* __restrict__ batch, int* gstart) {
    int i = blockIdx.x * 256 + threadIdx.x;   // grid covers 65536
    if (i < N_NODES) { deg[i] = 1.0f; cnt[i] = 0; cursor[i] = 0; }
    if (i < N_GRAPHS * F_OUT) out[i] = 0.f;
    if (i <= N_GRAPHS) {
        if (i == N_GRAPHS) gstart[i] = N_NODES;
        else {
            int lo = 0, hi = N_NODES;
            while (lo < hi) {
                int mid = (lo + hi) >> 1;
                if (batch[mid] < i) lo = mid + 1; else hi = mid;
            }
            gstart[i] = lo;
        }
    }
}

__global__ void k_deg(const int* __restrict__ dst, const float* __restrict__ ew,
                      float* deg, int* cnt) {
    int e = blockIdx.x * 256 + threadIdx.x;
    if (e < N_EDGES) {
        int d = dst[e];
        atomicAdd(&deg[d], ew[e]);
        atomicAdd(&cnt[d], 1);
    }
}

// ---------------- CSR build ----------------
__global__ __launch_bounds__(1024) void k_scan(const int* __restrict__ cnt, int* offs) {
    __shared__ int s[1024];
    int t = threadIdx.x;
    const int CH = (N_NODES + 1023) / 1024;
    int lo = t * CH, hi = min(lo + CH, N_NODES);
    int sum = 0;
    for (int i = lo; i < hi; i++) sum += cnt[i];
    s[t] = sum;
    __syncthreads();
    for (int off = 1; off < 1024; off <<= 1) {
        int v = (t >= off) ? s[t - off] : 0;
        __syncthreads();
        s[t] += v;
        __syncthreads();
    }
    int run = (t == 0) ? 0 : s[t - 1];
    for (int i = lo; i < hi; i++) { offs[i] = run; run += cnt[i]; }
    if (hi == N_NODES && lo < N_NODES) offs[N_NODES] = run;
}

// packed (src, weight-as-bits) per edge; dinv folded in via rsqrtf(deg)
__global__ void k_fill(const int* __restrict__ src, const int* __restrict__ dst,
                       const float* __restrict__ ew, const float* __restrict__ deg,
                       const int* __restrict__ offs, int* cursor,
                       int2* __restrict__ csre) {
    int e = blockIdx.x * 256 + threadIdx.x;
    if (e < N_EDGES) {
        int d = dst[e], s = src[e];
        int pos = offs[d] + atomicAdd(&cursor[d], 1);
        float w = rsqrtf(deg[s]) * ew[e] * rsqrtf(deg[d]);
        csre[pos] = make_int2(s, __float_as_int(w));
    }
}

// ---------------- conversions ----------------
__global__ void k_conv_x(const float* __restrict__ x, unsigned short* __restrict__ xb) {
    int idx = blockIdx.x * 256 + threadIdx.x;      // one thread = 8 cols
    int row = idx >> 6;                             // 64 chunks/row
    int c8 = (idx & 63) * 8;
    if (row >= N_PAD) return;
    ushort8v v;
    if (row < N_NODES) {
        const float* p = &x[(size_t)row * F_IN + c8];
#pragma unroll
        for (int i = 0; i < 8; i++) v[i] = f2bf(p[i]);
    } else {
#pragma unroll
        for (int i = 0; i < 8; i++) v[i] = 0;
    }
    *(ushort8v*)&xb[(size_t)row * F_IN + c8] = v;
}

// both W transposes in one launch: blockIdx.y < 16 -> W1 (K=512), else W2 (K=1024)
__global__ __launch_bounds__(256) void k_conv_wt(const float* __restrict__ W1,
                                                 unsigned short* __restrict__ Wt1,
                                                 const float* __restrict__ W2,
                                                 unsigned short* __restrict__ Wt2) {
    __shared__ float tile[32][33];
    const float* W;
    unsigned short* Wt;
    int K, k0;
    if (blockIdx.y < F_IN / 32) { W = W1; Wt = Wt1; K = F_IN;  k0 = blockIdx.y * 32; }
    else                        { W = W2; Wt = Wt2; K = F_OUT; k0 = (blockIdx.y - F_IN / 32) * 32; }
    int n0 = blockIdx.x * 32;
    int tx = threadIdx.x & 31;
    int ty = threadIdx.x >> 5;   // 0..7
#pragma unroll
    for (int i = 0; i < 32; i += 8)
        tile[ty + i][tx] = W[(size_t)(k0 + ty + i) * F_OUT + n0 + tx];
    __syncthreads();
#pragma unroll
    for (int i = 0; i < 32; i += 8)
        Wt[(size_t)(n0 + ty + i) * K + k0 + tx] = f2bf(tile[tx][ty + i]);
}

// ---------------- slab aggregation: 1 wave = 8 nodes x one 64-col slab ----------------
// 4x-unrolled edge loop (R9 config: VGPR ~16, occupancy ~76%).
__global__ __launch_bounds__(64) void k_aggr_slab(const unsigned short* __restrict__ xin,
                                                  const float* __restrict__ deg,
                                                  const int* __restrict__ offs,
                                                  const int2* __restrict__ csre,
                                                  const float* __restrict__ bias,
                                                  unsigned short* __restrict__ outp,
                                                  int F, int act) {
    const int bid = blockIdx.x;
    const int slab = bid & 7;
    const int ng = bid >> 3;
    const int lane = threadIdx.x;
    const int n = ng * 8 + (lane >> 3);
    const int c = blockIdx.y * 512 + slab * 64 + (lane & 7) * 8;

    if (n >= N_NODES) {
        ushort8v z;
#pragma unroll
        for (int i = 0; i < 8; i++) z[i] = 0;
        *(ushort8v*)&outp[(size_t)n * F + c] = z;
        return;
    }

    const float di = rsqrtf(deg[n]);
    const float wself = di * di;
    float a[8];
    {
        ushort8v v = *(const ushort8v*)&xin[(size_t)n * F + c];
#pragma unroll
        for (int i = 0; i < 8; i++) a[i] = bf2f(v[i]) * wself;
    }

    const int lo = offs[n], hi = offs[n + 1];
    int j = lo;
    for (; j + 4 <= hi; j += 4) {
        int2 e0 = csre[j + 0];
        int2 e1 = csre[j + 1];
        int2 e2 = csre[j + 2];
        int2 e3 = csre[j + 3];
        ushort8v u0 = *(const ushort8v*)&xin[(size_t)e0.x * F + c];
        ushort8v u1 = *(const ushort8v*)&xin[(size_t)e1.x * F + c];
        ushort8v u2 = *(const ushort8v*)&xin[(size_t)e2.x * F + c];
        ushort8v u3 = *(const ushort8v*)&xin[(size_t)e3.x * F + c];
        float w0 = __int_as_float(e0.y);
        float w1 = __int_as_float(e1.y);
        float w2 = __int_as_float(e2.y);
        float w3 = __int_as_float(e3.y);
#pragma unroll
        for (int i = 0; i < 8; i++) {
            a[i] += w0 * bf2f(u0[i]);
            a[i] += w1 * bf2f(u1[i]);
            a[i] += w2 * bf2f(u2[i]);
            a[i] += w3 * bf2f(u3[i]);
        }
    }
    for (; j < hi; j++) {
        int2 e = csre[j];
        float w = __int_as_float(e.y);
        ushort8v u = *(const ushort8v*)&xin[(size_t)e.x * F + c];
#pragma unroll
        for (int i = 0; i < 8; i++) a[i] += w * bf2f(u[i]);
    }

    ushort8v r;
    if (act) {
#pragma unroll
        for (int i = 0; i < 8; i++) r[i] = f2bf(fmaxf(a[i] + bias[c + i], 0.f));
    } else {
#pragma unroll
        for (int i = 0; i < 8; i++) r[i] = f2bf(a[i]);
    }
    *(ushort8v*)&outp[(size_t)n * F + c] = r;
}

// ---------------- bf16 MFMA GEMM (32x32x16): C_bf16[N_PAD,1024] = A @ Bt^T ----------------
// xcd=bid&7 owns row-blocks [xcd*20, xcd*20+20), col-block fastest -> 5.1 MB A-slice
// L2-resident per XCD.
// LDS swizzle v2 (bit-swapped): granule(r, kc) = r*4 + (swap2(kc) ^ ((r>>1)&3)).
// Read (ar, g=2*kk+kh): granule = ar*4 + (((kh<<1)|kk) ^ ((ar>>1)&3)) -> lanes l/l+32
// land in opposite bank-quad halves; conflict-free under paired-halves phasing
// (the 16x16 layout's measured-0 property, generalized).
__global__ __launch_bounds__(256) void k_gemm_bf16(const unsigned short* __restrict__ A,
                                                   const unsigned short* __restrict__ Bt,
                                                   unsigned short* __restrict__ C, int K,
                                                   const float* __restrict__ bias, int act) {
    __shared__ short As[128 * 32];
    __shared__ short Bs[128 * 32];
    const int bid = blockIdx.x;
    const int xcd = bid & 7;
    const int i2 = bid >> 3;                 // 0..159
    const int colb = i2 & 7;
    const int rowb = xcd * 20 + (i2 >> 3);   // exact partition: 8 XCD x 20 row-blocks
    const int row0 = rowb * 128;
    const int col0 = colb * 128;

    const int tid = threadIdx.x;
    const int lane = tid & 63;
    const int wave = tid >> 6;
    const int wm = wave >> 1, wn = wave & 1;
    const int l5 = lane & 31;
    const int kh = lane >> 5;                // k-half within a 16-k step

    f32x16 acc[2][2] = {};

    for (int k0 = 0; k0 < K; k0 += 32) {
#pragma unroll
        for (int it = 0; it < 2; it++) {
            int idx = it * 256 + tid;              // LDS granule id (lane-linear dest)
            int r = idx >> 2;
            int kcp = (idx & 3) ^ ((r >> 1) & 3);  // swapped-domain chunk
            int kc = ((kcp & 1) << 1) | (kcp >> 1);
            const unsigned short* ga = &A[(size_t)(row0 + r) * K + k0 + kc * 8];
            __builtin_amdgcn_global_load_lds(
                (const __attribute__((address_space(1))) void*)ga,
                (__attribute__((address_space(3))) void*)&As[idx * 8], 16, 0, 0);
            const unsigned short* gb = &Bt[(size_t)(col0 + r) * K + k0 + kc * 8];
            __builtin_amdgcn_global_load_lds(
                (const __attribute__((address_space(1))) void*)gb,
                (__attribute__((address_space(3))) void*)&Bs[idx * 8], 16, 0, 0);
        }
        __syncthreads();

        bf16x8 af[2][2], bfr[2][2];   // [kk][tile]
#pragma unroll
        for (int kk = 0; kk < 2; kk++) {
            int gp = (kh << 1) | kk;  // swapped-domain chunk for (g = 2*kk + kh)
#pragma unroll
            for (int i = 0; i < 2; i++) {
                int ar = wm * 64 + i * 32 + l5;
                int rho = gp ^ ((ar >> 1) & 3);
                af[kk][i] = *(const bf16x8*)&As[(ar * 4 + rho) * 8];
            }
#pragma unroll
            for (int j = 0; j < 2; j++) {
                int br = wn * 64 + j * 32 + l5;
                int rho = gp ^ ((br >> 1) & 3);
                bfr[kk][j] = *(const bf16x8*)&Bs[(br * 4 + rho) * 8];
            }
        }
#pragma unroll
        for (int kk = 0; kk < 2; kk++)
#pragma unroll
            for (int i = 0; i < 2; i++)
#pragma unroll
                for (int j = 0; j < 2; j++)
                    acc[i][j] = __builtin_amdgcn_mfma_f32_32x32x16_bf16(
                        af[kk][i], bfr[kk][j], acc[i][j], 0, 0, 0);
        __syncthreads();
    }

    // C/D: col=lane&31, row=(reg&3)+8*(reg>>2)+4*(lane>>5)  [m74/m101]
#pragma unroll
    for (int i = 0; i < 2; i++) {
#pragma unroll
        for (int j = 0; j < 2; j++) {
            int rbase = row0 + wm * 64 + i * 32 + kh * 4;
            int c = col0 + wn * 64 + j * 32 + l5;
            float bv = act ? bias[c] : 0.f;
#pragma unroll
            for (int reg = 0; reg < 16; reg++) {
                int rrow = rbase + (reg & 3) + 8 * (reg >> 2);
                float v = acc[i][j][reg];
                if (act) v = fmaxf(v + bv, 0.f);
                C[(size_t)rrow * F_OUT + c] = f2bf(v);
            }
        }
    }
}

// ---------------- node-parallel mean-pool ----------------
__global__ __launch_bounds__(256) void k_pool(const unsigned short* __restrict__ h,
                                              const int* __restrict__ batch,
                                              const int* __restrict__ gstart,
                                              float* __restrict__ out) {
    const int r0 = blockIdx.x * 64;
    const int rowsub = threadIdx.x >> 7;           // 0..1
    const int c = (threadIdx.x & 127) * 8;         // full 1024-col row
    const int rend = min(r0 + 64, N_NODES);
    int row = r0 + rowsub;
    if (row >= rend) return;

    float a[8] = {};
    int gcur = batch[row];
    for (; row < rend; row += 2) {
        int g = batch[row];
        if (g != gcur) {
            float inv = 1.0f / (float)max(gstart[gcur + 1] - gstart[gcur], 1);
#pragma unroll
            for (int i = 0; i < 8; i++) {
                atomicAdd(&out[(size_t)gcur * F_OUT + c + i], a[i] * inv);
                a[i] = 0.f;
            }
            gcur = g;
        }
        ushort8v v = *(const ushort8v*)&h[(size_t)row * F_OUT + c];
#pragma unroll
        for (int i = 0; i < 8; i++) a[i] += bf2f(v[i]);
    }
    float inv = 1.0f / (float)max(gstart[gcur + 1] - gstart[gcur], 1);
#pragma unroll
    for (int i = 0; i < 8; i++)
        atomicAdd(&out[(size_t)gcur * F_OUT + c + i], a[i] * inv);
}

// ---------------- launch ----------------
extern "C" void kernel_launch(void* const* d_in, const int* in_sizes, int n_in,
                              void* d_out, int out_size, void* d_ws, size_t ws_size,
                              hipStream_t stream) {
    const float* x    = (const float*)d_in[0];
    const int* ei     = (const int*)d_in[1];
    const float* ew   = (const float*)d_in[2];
    const int* batch  = (const int*)d_in[3];
    const float* W1   = (const float*)d_in[4];
    const float* b1   = (const float*)d_in[5];
    const float* W2   = (const float*)d_in[6];
    const float* b2   = (const float*)d_in[7];
    float* out = (float*)d_out;

    const int* src = ei;
    const int* dst = ei + N_EDGES;

    char* ws = (char*)d_ws;
    const size_t SZ_XB  = (size_t)N_PAD * F_IN * 2;    // 21.0 MB
    const size_t SZ_AX  = (size_t)N_PAD * F_IN * 2;    // 21.0 MB
    const size_t SZ_WT1 = (size_t)F_OUT * F_IN * 2;    //  1 MB
    const size_t SZ_WT2 = (size_t)F_OUT * F_OUT * 2;   //  2 MB
    const size_t SZ_B   = (size_t)N_PAD * F_OUT * 2;   // 41.9 MB
    unsigned short* xb  = (unsigned short*)(ws);
    unsigned short* ax  = (unsigned short*)(ws + SZ_XB);
    unsigned short* Wt1 = (unsigned short*)(ws + SZ_XB + SZ_AX);
    unsigned short* Wt2 = (unsigned short*)(ws + SZ_XB + SZ_AX + SZ_WT1);
    unsigned short* h1  = (unsigned short*)(ws + SZ_XB + SZ_AX + SZ_WT1 + SZ_WT2);
    unsigned short* xw2 = (unsigned short*)(ws + SZ_XB + SZ_AX + SZ_WT1 + SZ_WT2 + SZ_B);
    unsigned short* h2  = (unsigned short*)(ws);       // aliases xb/ax (dead in phase B)
    size_t off = SZ_XB + SZ_AX + SZ_WT1 + SZ_WT2 + 2 * SZ_B;
    auto alloc = [&](size_t bytes) -> void* {
        void* p = ws + off;
        off += (bytes + 255) & ~(size_t)255;
        return p;
    };
    float* deg    = (float*)alloc((size_t)N_NODES * 4);
    int*   cnt    = (int*)  alloc((size_t)N_NODES * 4);
    int*   offs   = (int*)  alloc((size_t)(N_NODES + 1) * 4);
    int*   cursor = (int*)  alloc((size_t)N_NODES * 4);
    int2*  csre   = (int2*) alloc((size_t)N_EDGES * 8);
    int*   gstart = (int*)  alloc((size_t)(N_GRAPHS + 1) * 4);

    const int nb_e = (N_EDGES + 255) / 256;

    k_setup<<<(N_GRAPHS * F_OUT + 255) / 256, 256, 0, stream>>>(deg, cnt, cursor, out,
                                                                batch, gstart);
    k_deg<<<nb_e, 256, 0, stream>>>(dst, ew, deg, cnt);
    k_scan<<<1, 1024, 0, stream>>>(cnt, offs);
    k_fill<<<nb_e, 256, 0, stream>>>(src, dst, ew, deg, offs, cursor, csre);

    // conversions
    k_conv_x<<<(N_PAD * (F_IN / 8) + 255) / 256, 256, 0, stream>>>(x, xb);
    k_conv_wt<<<dim3(F_OUT / 32, F_IN / 32 + F_OUT / 32), 256, 0, stream>>>(W1, Wt1, W2, Wt2);

    // layer 1: aggregate X first (reassociated), then GEMM with fused bias+relu
    k_aggr_slab<<<dim3((N_PAD / 8) * 8, 1), 64, 0, stream>>>(xb, deg, offs, csre,
                                                             (const float*)nullptr, ax, F_IN, 0);
    const int gemm_blocks = (N_PAD / 128) * (F_OUT / 128);   // 1280
    k_gemm_bf16<<<gemm_blocks, 256, 0, stream>>>(ax, Wt1, h1, F_IN, b1, 1);
    // layer 2: GEMM then slab aggregation with fused bias+relu -> h2
    k_gemm_bf16<<<gemm_blocks, 256, 0, stream>>>(h1, Wt2, xw2, F_OUT, (const float*)nullptr, 0);
    k_aggr_slab<<<dim3((N_PAD / 8) * 8, 2), 64, 0, stream>>>(xw2, deg, offs, csre, b2, h2, F_OUT, 1);
    // pool (node-parallel)
    k_pool<<<(N_NODES + 63) / 64, 256, 0, stream>>>(h2, batch, gstart, out);
}